// Round 1
// 717.512 us; speedup vs baseline: 1.1402x; 1.1402x over previous
//
#include <hip/hip_runtime.h>

// mLSTM block, bf16-MFMA, R5: gemm_gates rebuilt as 128M x (32N x 6 gates),
// BK=64 (was 64M x 64N x 6, BK=32). Per wave per barrier-pair: 48 MFMAs
// (was 24); staged LDS bytes per MFMA 0.29 -> 0.21 KB; K-loop 32 -> 16
// iterations. acc stays 96 regs/lane (occupancy unchanged at 2 waves/SIMD,
// which is the fused-gate accumulator floor).
// Tokens M = 16384, D = 1024, P = 2048, H = 1024.
//
// LDS swizzle (gemm_bt, rows = 64 B = 4 chunks of 16 B): chunk c of row r
// stored at slot c ^ ((r>>1)&3), realized by swizzling the SOURCE address
// (global_load_lds forces dest = base + lane*16). Readers use
// quad ^ ((l15>>1)&3); all row offsets are multiples of 16 so the swizzle
// term depends only on l15. Conflict-free under the 8-lane service model.
//
// gemm_gates swizzle (rows = 128 B = 8 chunks of 16 B): chunk c of row r
// stored at slot c ^ (r&7). A staging wave-chunk covers 8 rows (lane>>3 =
// row, lane&7 = slot, source chunk = (lane&7)^(lane>>3)). Fragment readers
// want source chunk ks*4+quad at row ...+l15 -> read slot
// (ks*4+quad)^(l15&7); row offsets are multiples of 8/16 so only l15
// matters. Lanes 0..7 hit slots {0..7}*16B -> all 32 banks once.
//
// Workspace (MiB offsets), total 150 MiB:
//   [0,32)    xn -> ht (xn dead after up-GEMM) -> y (same-thread r/w alias)
//   [32,96)   xup
//   [96,128)  xadj
//   [128,132) WupT  [132,136) WadjT  [136,148) Wcat  [148,150) WdnT

typedef unsigned short u16;
typedef __attribute__((ext_vector_type(4))) unsigned short u16x4;
typedef __attribute__((ext_vector_type(8))) __bf16 bf16x8;
typedef __attribute__((ext_vector_type(4))) float f32x4;

__device__ __forceinline__ float bf2f(u16 u) {
    union { unsigned int i; float f; } c; c.i = ((unsigned int)u) << 16; return c.f;
}
__device__ __forceinline__ u16 f2bf(float f) {
    union { float f; unsigned int i; } c; c.f = f;
    unsigned int lsb = (c.i >> 16) & 1u;
    c.i += 0x7fffu + lsb;                 // round-to-nearest-even
    return (u16)(c.i >> 16);
}
__device__ __forceinline__ float sigmoidf(float z) {
    return 1.0f / (1.0f + __expf(-z));
}

// async global->LDS, 16B per lane; LDS dest = wave-uniform base + lane*16
#define GLDS16(gp, lp)                                                        \
    __builtin_amdgcn_global_load_lds(                                         \
        (__attribute__((address_space(1))) void*)(void*)(gp),                 \
        (__attribute__((address_space(3))) void*)(lp), 16, 0, 0)

#define BM 128
#define BN 128
#define BK 32

// C[M,N] = A[M,K] @ B[K,N] with Bt = B^T stored [N,K], all bf16, fp32 acc.
// MODE 0: out bf16 = (acc + bias[n]) * scale
// MODE 1: out f32  = (acc + bias[n]) * scale + resid[m*N+n]
template <int MODE>
__global__ __launch_bounds__(256) void gemm_bt(
    const u16* __restrict__ A, const u16* __restrict__ Bt,
    const float* __restrict__ bias, const float* __restrict__ resid,
    void* __restrict__ out, int M, int N, int K, float scale)
{
    __shared__ __align__(16) u16 As[BM * BK];
    __shared__ __align__(16) u16 Bs[BN * BK];

    const int tid  = threadIdx.x;
    const int lane = tid & 63;
    const int wave = tid >> 6;
    const int l15  = lane & 15;
    const int quad = lane >> 4;

    const long bm = (long)blockIdx.y * BM;
    const long bn = (long)blockIdx.x * BN;
    const int  wm = (wave >> 1) * 64;   // wave's 64x64 quadrant
    const int  wn = (wave & 1) * 64;

    f32x4 acc[4][4] = {};

    // staging: thread tid covers row tid>>2; SOURCE chunk is swizzled so the
    // identity LDS placement (lane*16) realizes the XOR-swizzled layout.
    const int  r0 = tid >> 2;
    const int  ck = (((tid & 3) ^ ((tid >> 3) & 3)) * 8);
    const u16* ga0 = A  + (bm + r0) * (long)K + ck;
    const u16* gb0 = Bt + (bn + r0) * (long)K + ck;
    u16* lA = &As[(wave * 64) * 8];
    u16* lB = &Bs[(wave * 64) * 8];

    const int q8s = (quad ^ ((l15 >> 1) & 3)) * 8;   // swizzled chunk offset

    for (int k0 = 0; k0 < K; k0 += BK) {
        GLDS16(ga0 + k0, lA);
        GLDS16(ga0 + k0 + 64 * (long)K, lA + 256 * 8);
        GLDS16(gb0 + k0, lB);
        GLDS16(gb0 + k0 + 64 * (long)K, lB + 256 * 8);
        __syncthreads();

        bf16x8 af[4], bfr[4];
#pragma unroll
        for (int t = 0; t < 4; ++t) {
            af[t]  = *(const bf16x8*)&As[(wm + t * 16 + l15) * BK + q8s];
            bfr[t] = *(const bf16x8*)&Bs[(wn + t * 16 + l15) * BK + q8s];
        }
#pragma unroll
        for (int mt = 0; mt < 4; ++mt)
#pragma unroll
            for (int nt = 0; nt < 4; ++nt)
                acc[mt][nt] = __builtin_amdgcn_mfma_f32_16x16x32_bf16(
                    af[mt], bfr[nt], acc[mt][nt], 0, 0, 0);
        __syncthreads();
    }

    // C/D layout: col = lane&15, row = quad*4 + reg
#pragma unroll
    for (int nt = 0; nt < 4; ++nt) {
        const long n  = bn + wn + nt * 16 + l15;
        const float bv = bias[n];
#pragma unroll
        for (int mt = 0; mt < 4; ++mt) {
            const long m0 = bm + wm + mt * 16 + quad * 4;
#pragma unroll
            for (int r = 0; r < 4; ++r) {
                const long idx = (m0 + r) * N + n;
                const float val = (acc[mt][nt][r] + bv) * scale;
                if (MODE == 0) ((u16*)out)[idx] = f2bf(val);
                else           ((float*)out)[idx] = val + resid[idx];
            }
        }
    }
}

// Fused 6-way gate GEMM + mLSTM gate math.
// A = xadj [M,K], Wcat = 6 gate weights transposed, [6*1024, K] (order
// q,k,v,i,f,o). Block = 128(M) x 32(N) of ALL six projections, BK=64,
// 256 threads / 4 waves. Wave w owns m-half (w>>1)*64 and n-half (w&1)*16:
// per BK-step 8 A-frag reads + 12 B-frag reads feed 48 MFMAs. f32 accs,
// gate math in-register, writes ht bf16 [M,1024].
__global__ __launch_bounds__(256) void gemm_gates(
    const u16* __restrict__ A, const u16* __restrict__ Wcat,
    const float* __restrict__ bq_, const float* __restrict__ bk_,
    const float* __restrict__ bv_, const float* __restrict__ bi_,
    const float* __restrict__ bf_, const float* __restrict__ bo_,
    u16* __restrict__ ht, int M, int N, int K)
{
    __shared__ __align__(16) u16 As[128 * 64];       // 16 KB
    __shared__ __align__(16) u16 Bs[6 * 32 * 64];    // 24 KB

    const int tid  = threadIdx.x;
    const int lane = tid & 63;
    const int wave = tid >> 6;          // 0..3
    const int l15  = lane & 15;
    const int quad = lane >> 4;

    const long bm = (long)blockIdx.y * 128;
    const long bn = (long)blockIdx.x * 32;

    f32x4 acc[6][4] = {};

    // ---- staging: 1 KB wave-chunks of 8 rows (rows are 128 B = 64 u16).
    // lane covers row lane>>3 of the chunk, slot lane&7; source chunk is
    // (lane&7)^(lane>>3) so identity LDS placement realizes slot = c^(r&7).
    const int  rr = lane >> 3;                       // row within 8-row group
    const int  ck = (((lane & 7) ^ rr) * 8);         // swizzled source (u16)

    const u16* gaj[4];                               // A: 16 chunks, 4/wave
    u16* lAj[4];
#pragma unroll
    for (int j = 0; j < 4; ++j) {
        const int c = wave * 4 + j;                  // chunk 0..15
        gaj[j] = A + (bm + c * 8 + rr) * (long)K + ck;
        lAj[j] = &As[c * 512];
    }
    const u16* gbj[6];                               // B: 24 chunks, 6/wave
    u16* lBj[6];
#pragma unroll
    for (int j = 0; j < 6; ++j) {
        const int c = wave * 6 + j;                  // chunk 0..23
        const int g = c >> 2;                        // gate
        const int r = (c & 3) * 8 + rr;              // row in gate tile 0..31
        gbj[j] = Wcat + ((long)g * 1024 + bn + r) * (long)K + ck;
        lBj[j] = &Bs[c * 512];
    }

    const int mh = (wave >> 1) * 64;                 // wave m-half
    const int nb = (wave & 1) * 16;                  // wave n-half
    const int l7 = l15 & 7;

    for (int k0 = 0; k0 < K; k0 += 64) {
#pragma unroll
        for (int j = 0; j < 4; ++j) GLDS16(gaj[j] + k0, lAj[j]);
#pragma unroll
        for (int j = 0; j < 6; ++j) GLDS16(gbj[j] + k0, lBj[j]);
        __syncthreads();

#pragma unroll
        for (int ks = 0; ks < 2; ++ks) {
            const int so = ((ks * 4 + quad) ^ l7) * 8;   // swizzled slot (u16)
            bf16x8 af[4];
#pragma unroll
            for (int t = 0; t < 4; ++t)
                af[t] = *(const bf16x8*)&As[(mh + t * 16 + l15) * 64 + so];
#pragma unroll
            for (int g = 0; g < 6; ++g) {
                const bf16x8 bfrag =
                    *(const bf16x8*)&Bs[(g * 32 + nb + l15) * 64 + so];
#pragma unroll
                for (int t = 0; t < 4; ++t)
                    acc[g][t] = __builtin_amdgcn_mfma_f32_16x16x32_bf16(
                        af[t], bfrag, acc[g][t], 0, 0, 0);
            }
        }
        __syncthreads();
    }

    // C/D layout: col = lane&15, row = quad*4 + reg. One n per lane.
    const long n = bn + nb + l15;
    const float bqn = bq_[n], bkn = bk_[n], bvn = bv_[n];
    const float bin = bi_[n], bfn = bf_[n], bon = bo_[n];
#pragma unroll
    for (int t = 0; t < 4; ++t) {
        const long m0 = bm + mh + t * 16 + quad * 4;
#pragma unroll
        for (int r = 0; r < 4; ++r) {
            const float qf = acc[0][t][r] + bqn;
            const float kf = (acc[1][t][r] + bkn) * 0.125f;
            const float vf = acc[2][t][r] + bvn;
            const float fi = acc[3][t][r] + bin;
            const float ff = acc[4][t][r] + bfn;
            const float osig = sigmoidf(acc[5][t][r] + bon);
            const float mx = fmaxf(ff, fi);
            const float fe = __expf(ff - mx);
            const float ct = fe * vf * kf;
            const float h  = osig * (ct * qf) / fmaxf(fabsf(kf * qf), 1.0f);
            ht[(m0 + r) * N + n] = f2bf(h);
        }
    }
}

// LayerNorm over 1024 cols, fp32 in -> bf16 out. One 256-thread block per row.
__global__ __launch_bounds__(256) void ln_in_kernel(
    const float* __restrict__ x, const float* __restrict__ g,
    const float* __restrict__ b, u16* __restrict__ xn)
{
    const long row = blockIdx.x;
    const int  tid = threadIdx.x;
    const float4 v = ((const float4*)(x + row * 1024))[tid];
    float s  = v.x + v.y + v.z + v.w;
    float s2 = v.x * v.x + v.y * v.y + v.z * v.z + v.w * v.w;
#pragma unroll
    for (int off = 32; off > 0; off >>= 1) {
        s  += __shfl_down(s, off);
        s2 += __shfl_down(s2, off);
    }
    __shared__ float red[8];
    const int wave = tid >> 6;
    if ((tid & 63) == 0) { red[wave] = s; red[4 + wave] = s2; }
    __syncthreads();
    if (tid == 0) {
        const float S  = red[0] + red[1] + red[2] + red[3];
        const float S2 = red[4] + red[5] + red[6] + red[7];
        const float mu = S * (1.0f / 1024.0f);
        const float var = S2 * (1.0f / 1024.0f) - mu * mu;
        red[0] = mu; red[1] = rsqrtf(var + 1e-3f);
    }
    __syncthreads();
    const float mu = red[0], rstd = red[1];
    const int c = tid * 4;
    u16x4 o;
    o.x = f2bf((v.x - mu) * rstd * g[c + 0] + b[c + 0]);
    o.y = f2bf((v.y - mu) * rstd * g[c + 1] + b[c + 1]);
    o.z = f2bf((v.z - mu) * rstd * g[c + 2] + b[c + 2]);
    o.w = f2bf((v.w - mu) * rstd * g[c + 3] + b[c + 3]);
    *(u16x4*)(xn + row * 1024 + c) = o;
}

// transpose + f32->bf16: W[K,N] -> Wt[N,K]
__global__ __launch_bounds__(256) void convT_kernel(
    const float* __restrict__ W, u16* __restrict__ Wt, int K, int N)
{
    __shared__ float t[32][33];
    const int tx = threadIdx.x & 31;
    const int ty = threadIdx.x >> 5;
    const long bn = (long)blockIdx.x * 32;
    const long bk = (long)blockIdx.y * 32;
#pragma unroll
    for (int j = 0; j < 4; ++j)
        t[ty + j * 8][tx] = W[(bk + ty + j * 8) * N + bn + tx];
    __syncthreads();
#pragma unroll
    for (int j = 0; j < 4; ++j)
        Wt[(bn + ty + j * 8) * K + bk + tx] = f2bf(t[tx][ty + j * 8]);
}

// LN2 over ht rows + sigmoid(xadj) product. y may alias ht (same-thread r/w).
__global__ __launch_bounds__(256) void ln2_kernel(
    const u16* __restrict__ ht, const u16* __restrict__ xadj,
    const float* __restrict__ g2, const float* __restrict__ b2,
    u16* __restrict__ y)
{
    const long base = (long)blockIdx.x * 1024;
    const int  tid = threadIdx.x;
    const int  c = tid * 4;
    const u16x4 hv = *(const u16x4*)&ht[base + c];
    const u16x4 xv = *(const u16x4*)&xadj[base + c];

    float h[4];
    float s = 0.0f, s2 = 0.0f;
#pragma unroll
    for (int j = 0; j < 4; ++j) {
        h[j] = bf2f(hv[j]);
        s += h[j]; s2 += h[j] * h[j];
    }
#pragma unroll
    for (int off = 32; off > 0; off >>= 1) {
        s  += __shfl_down(s, off);
        s2 += __shfl_down(s2, off);
    }
    __shared__ float red[8];
    const int wave = tid >> 6;
    if ((tid & 63) == 0) { red[wave] = s; red[4 + wave] = s2; }
    __syncthreads();
    if (tid == 0) {
        const float S  = red[0] + red[1] + red[2] + red[3];
        const float S2 = red[4] + red[5] + red[6] + red[7];
        const float mu = S * (1.0f / 1024.0f);
        const float var = S2 * (1.0f / 1024.0f) - mu * mu;
        red[0] = mu; red[1] = rsqrtf(var + 1e-3f);
    }
    __syncthreads();
    const float mu = red[0], rstd = red[1];
    u16x4 o;
#pragma unroll
    for (int j = 0; j < 4; ++j)
        o[j] = f2bf(((h[j] - mu) * rstd * g2[c + j] + b2[c + j]) * sigmoidf(bf2f(xv[j])));
    *(u16x4*)&y[base + c] = o;
}

extern "C" void kernel_launch(void* const* d_in, const int* in_sizes, int n_in,
                              void* d_out, int out_size, void* d_ws, size_t ws_size,
                              hipStream_t stream)
{
    const float* x    = (const float*)d_in[0];
    const float* g1   = (const float*)d_in[1];
    const float* b1   = (const float*)d_in[2];
    const float* Wup  = (const float*)d_in[3];
    const float* bup  = (const float*)d_in[4];
    const float* Wadj = (const float*)d_in[5];
    const float* badj = (const float*)d_in[6];
    const float* Wq = (const float*)d_in[7];   const float* bq = (const float*)d_in[8];
    const float* Wk = (const float*)d_in[9];   const float* bk = (const float*)d_in[10];
    const float* Wv = (const float*)d_in[11];  const float* bv = (const float*)d_in[12];
    const float* Wi = (const float*)d_in[13];  const float* bi = (const float*)d_in[14];
    const float* Wf = (const float*)d_in[15];  const float* bf = (const float*)d_in[16];
    const float* Wo = (const float*)d_in[17];  const float* bo = (const float*)d_in[18];
    const float* g2 = (const float*)d_in[19];  const float* b2 = (const float*)d_in[20];
    const float* Wdn = (const float*)d_in[21]; const float* bdn = (const float*)d_in[22];

    const int M = 8 * 2048;     // 16384 tokens
    const int D = 1024, P = 2048, H = 1024;

    char* ws = (char*)d_ws;
    const size_t MB = 1024 * 1024;
    u16* xn    = (u16*)(ws + 0);
    u16* xup   = (u16*)(ws + 32 * MB);
    u16* xadj  = (u16*)(ws + 96 * MB);
    u16* htb   = (u16*)(ws + 0);          // reuse xn (dead after up-GEMM)
    u16* yb    = (u16*)(ws + 0);          // alias ht (same-thread read-then-write)
    u16* WupT  = (u16*)(ws + 128 * MB);   // [2048,1024] 4MB
    u16* WadjT = (u16*)(ws + 132 * MB);   // [1024,2048] 4MB
    u16* Wcat  = (u16*)(ws + 136 * MB);   // [6*1024,1024] 12MB, order q,k,v,i,f,o
    u16* WdnT  = (u16*)(ws + 148 * MB);   // [1024,1024] 2MB -> ends at 150 MiB

    // 1) LN1
    ln_in_kernel<<<M, 256, 0, stream>>>(x, g1, b1, xn);

    // 2) weight transpose+convert (gates go into concatenated Wcat)
    convT_kernel<<<dim3(P / 32, D / 32), 256, 0, stream>>>(Wup,  WupT,  D, P);
    convT_kernel<<<dim3(H / 32, P / 32), 256, 0, stream>>>(Wadj, WadjT, P, H);
    convT_kernel<<<dim3(H / 32, H / 32), 256, 0, stream>>>(Wq, Wcat + 0 * H * H, H, H);
    convT_kernel<<<dim3(H / 32, H / 32), 256, 0, stream>>>(Wk, Wcat + 1 * H * H, H, H);
    convT_kernel<<<dim3(H / 32, H / 32), 256, 0, stream>>>(Wv, Wcat + 2 * H * H, H, H);
    convT_kernel<<<dim3(H / 32, H / 32), 256, 0, stream>>>(Wi, Wcat + 3 * H * H, H, H);
    convT_kernel<<<dim3(H / 32, H / 32), 256, 0, stream>>>(Wf, Wcat + 4 * H * H, H, H);
    convT_kernel<<<dim3(H / 32, H / 32), 256, 0, stream>>>(Wo, Wcat + 5 * H * H, H, H);
    convT_kernel<<<dim3(D / 32, H / 32), 256, 0, stream>>>(Wdn, WdnT, H, D);

    // 3) up- and adj-GEMMs
    gemm_bt<0><<<dim3(P / BN, M / BM), 256, 0, stream>>>(xn,  WupT,  bup,  nullptr, xup,  M, P, D, 1.0f);
    gemm_bt<0><<<dim3(H / BN, M / BM), 256, 0, stream>>>(xup, WadjT, badj, nullptr, xadj, M, H, P, 1.0f);

    // 4) fused six-gate GEMM + gate math -> ht (128M x 32N x 6g, BK=64)
    gemm_gates<<<dim3(H / 32, M / 128), 256, 0, stream>>>(
        xadj, Wcat, bq, bk, bv, bi, bf, bo, htb, M, H, H);

    // 5) LN2 + sigmoid(xadj) -> y
    ln2_kernel<<<M, 256, 0, stream>>>(htb, xadj, g2, b2, yb);

    // 6) down-proj + bias + residual, fp32 out
    gemm_bt<1><<<dim3(D / BN, M / BM), 256, 0, stream>>>(yb, WdnT, bdn, x, (float*)d_out, M, D, H, 1.0f);
}

// Round 2
// 662.433 us; speedup vs baseline: 1.2351x; 1.0831x over previous
//
#include <hip/hip_runtime.h>

// mLSTM block, bf16-MFMA, R6: 2-deep counted-vmcnt software pipeline (T4) in
// both GEMM kernels. Double-buffered LDS; stage for tile t+2 issued right
// after all waves finish reading buf[t&1]; main loop never drains vmcnt to 0.
// Sync pattern per iter:
//   s_waitcnt vmcnt(N)  // N = loads/tile still in flight (tile t+1's)
//   s_barrier           // all waves passed their own vmcnt -> tile t visible
//   ds_read frags ; s_waitcnt lgkmcnt(0) ; s_barrier   // all reads done
//   issue global_load_lds for tile t+2 into buf[t&1]   // lands >=2 iters later
//   MFMA cluster
// Tokens M = 16384, D = 1024, P = 2048, H = 1024.
//
// LDS swizzle (gemm_bt, rows = 64 B = 4 chunks of 16 B): chunk c of row r
// stored at slot c ^ ((r>>1)&3), realized by swizzling the SOURCE address
// (global_load_lds forces dest = base + lane*16). Readers use
// quad ^ ((l15>>1)&3). Conflict-free (measured 0 conflicts).
//
// gemm_gates swizzle (rows = 128 B = 8 chunks of 16 B): chunk c of row r
// stored at slot c ^ (r&7); staging lane covers row lane>>3, slot lane&7,
// source chunk (lane&7)^(lane>>3). Readers use (ks*4+quad)^(l15&7).
// Buffer offsets are multiples of 128 B -> bank pattern unchanged by dbuf.
//
// Workspace (MiB offsets), total 150 MiB:
//   [0,32)    xn -> ht (xn dead after up-GEMM) -> y (same-thread r/w alias)
//   [32,96)   xup
//   [96,128)  xadj
//   [128,132) WupT  [132,136) WadjT  [136,148) Wcat  [148,150) WdnT

typedef unsigned short u16;
typedef __attribute__((ext_vector_type(4))) unsigned short u16x4;
typedef __attribute__((ext_vector_type(8))) __bf16 bf16x8;
typedef __attribute__((ext_vector_type(4))) float f32x4;

__device__ __forceinline__ float bf2f(u16 u) {
    union { unsigned int i; float f; } c; c.i = ((unsigned int)u) << 16; return c.f;
}
__device__ __forceinline__ u16 f2bf(float f) {
    union { float f; unsigned int i; } c; c.f = f;
    unsigned int lsb = (c.i >> 16) & 1u;
    c.i += 0x7fffu + lsb;                 // round-to-nearest-even
    return (u16)(c.i >> 16);
}
__device__ __forceinline__ float sigmoidf(float z) {
    return 1.0f / (1.0f + __expf(-z));
}

// async global->LDS, 16B per lane; LDS dest = wave-uniform base + lane*16
#define GLDS16(gp, lp)                                                        \
    __builtin_amdgcn_global_load_lds(                                         \
        (__attribute__((address_space(1))) void*)(void*)(gp),                 \
        (__attribute__((address_space(3))) void*)(lp), 16, 0, 0)

#define BM 128
#define BN 128
#define BK 32

// C[M,N] = A[M,K] @ B[K,N] with Bt = B^T stored [N,K], all bf16, fp32 acc.
// MODE 0: out bf16 = (acc + bias[n]) * scale
// MODE 1: out f32  = (acc + bias[n]) * scale + resid[m*N+n]
template <int MODE>
__global__ __launch_bounds__(256) void gemm_bt(
    const u16* __restrict__ A, const u16* __restrict__ Bt,
    const float* __restrict__ bias, const float* __restrict__ resid,
    void* __restrict__ out, int M, int N, int K, float scale)
{
    __shared__ __align__(16) u16 As[2 * BM * BK];   // 2 x 8 KB
    __shared__ __align__(16) u16 Bs[2 * BN * BK];   // 2 x 8 KB

    const int tid  = threadIdx.x;
    const int lane = tid & 63;
    const int wave = tid >> 6;
    const int l15  = lane & 15;
    const int quad = lane >> 4;

    const long bm = (long)blockIdx.y * BM;
    const long bn = (long)blockIdx.x * BN;
    const int  wm = (wave >> 1) * 64;   // wave's 64x64 quadrant
    const int  wn = (wave & 1) * 64;

    f32x4 acc[4][4] = {};

    // staging: thread tid covers row tid>>2; SOURCE chunk is swizzled so the
    // identity LDS placement (lane*16) realizes the XOR-swizzled layout.
    const int  r0 = tid >> 2;
    const int  ck = (((tid & 3) ^ ((tid >> 3) & 3)) * 8);
    const u16* ga0 = A  + (bm + r0) * (long)K + ck;
    const u16* gb0 = Bt + (bn + r0) * (long)K + ck;
    const int  ldst = wave * 512;        // wave's dest inside a buffer (u16)

    auto stage = [&](int t_, int b_) {
        const long kof = (long)t_ * BK;
        u16* dA = &As[b_ * (BM * BK) + ldst];
        u16* dB = &Bs[b_ * (BN * BK) + ldst];
        GLDS16(ga0 + kof, dA);
        GLDS16(ga0 + kof + 64 * (long)K, dA + 2048);
        GLDS16(gb0 + kof, dB);
        GLDS16(gb0 + kof + 64 * (long)K, dB + 2048);
    };

    const int q8s = (quad ^ ((l15 >> 1) & 3)) * 8;   // swizzled chunk offset
    const int nk  = K / BK;                          // >= 32 for all shapes

    stage(0, 0);    // 4 loads
    stage(1, 1);    // 4 loads -> 8 in flight

    for (int t = 0; t < nk; ++t) {
        const int cur = t & 1;
        if (t + 1 < nk) asm volatile("s_waitcnt vmcnt(4)" ::: "memory");
        else            asm volatile("s_waitcnt vmcnt(0)" ::: "memory");
        __builtin_amdgcn_s_barrier();

        bf16x8 af[4], bfr[4];
#pragma unroll
        for (int t4 = 0; t4 < 4; ++t4) {
            af[t4]  = *(const bf16x8*)&As[cur * (BM * BK) + (wm + t4 * 16 + l15) * BK + q8s];
            bfr[t4] = *(const bf16x8*)&Bs[cur * (BN * BK) + (wn + t4 * 16 + l15) * BK + q8s];
        }
        asm volatile("s_waitcnt lgkmcnt(0)" ::: "memory");
        __builtin_amdgcn_s_barrier();
        if (t + 2 < nk) stage(t + 2, cur);

#pragma unroll
        for (int mt = 0; mt < 4; ++mt)
#pragma unroll
            for (int nt = 0; nt < 4; ++nt)
                acc[mt][nt] = __builtin_amdgcn_mfma_f32_16x16x32_bf16(
                    af[mt], bfr[nt], acc[mt][nt], 0, 0, 0);
    }

    // C/D layout: col = lane&15, row = quad*4 + reg
#pragma unroll
    for (int nt = 0; nt < 4; ++nt) {
        const long n  = bn + wn + nt * 16 + l15;
        const float bv = bias[n];
#pragma unroll
        for (int mt = 0; mt < 4; ++mt) {
            const long m0 = bm + wm + mt * 16 + quad * 4;
#pragma unroll
            for (int r = 0; r < 4; ++r) {
                const long idx = (m0 + r) * N + n;
                const float val = (acc[mt][nt][r] + bv) * scale;
                if (MODE == 0) ((u16*)out)[idx] = f2bf(val);
                else           ((float*)out)[idx] = val + resid[idx];
            }
        }
    }
}

// Fused 6-way gate GEMM + mLSTM gate math.
// A = xadj [M,K], Wcat = 6 gate weights transposed, [6*1024, K] (order
// q,k,v,i,f,o). Block = 128(M) x 32(N) of ALL six projections, BK=64,
// 256 threads / 4 waves. Wave w owns m-half (w>>1)*64 and n-half (w&1)*16:
// per BK-step 8 A-frag reads + 12 B-frag reads feed 48 MFMAs. f32 accs,
// gate math in-register, writes ht bf16 [M,1024]. 2-deep pipelined.
__global__ __launch_bounds__(256) void gemm_gates(
    const u16* __restrict__ A, const u16* __restrict__ Wcat,
    const float* __restrict__ bq_, const float* __restrict__ bk_,
    const float* __restrict__ bv_, const float* __restrict__ bi_,
    const float* __restrict__ bf_, const float* __restrict__ bo_,
    u16* __restrict__ ht, int M, int N, int K)
{
    __shared__ __align__(16) u16 As[2 * 128 * 64];       // 2 x 16 KB
    __shared__ __align__(16) u16 Bs[2 * 6 * 32 * 64];    // 2 x 24 KB

    const int tid  = threadIdx.x;
    const int lane = tid & 63;
    const int wave = tid >> 6;          // 0..3
    const int l15  = lane & 15;
    const int quad = lane >> 4;

    const long bm = (long)blockIdx.y * 128;
    const long bn = (long)blockIdx.x * 32;

    f32x4 acc[6][4] = {};

    // ---- staging: 1 KB wave-chunks of 8 rows (rows are 128 B = 64 u16).
    // lane covers row lane>>3 of the chunk, slot lane&7; source chunk is
    // (lane&7)^(lane>>3) so identity LDS placement realizes slot = c^(r&7).
    const int  rr = lane >> 3;                       // row within 8-row group
    const int  ck = (((lane & 7) ^ rr) * 8);         // swizzled source (u16)

    const u16* gaj[4];                               // A: 16 chunks, 4/wave
    int lAo[4];
#pragma unroll
    for (int j = 0; j < 4; ++j) {
        const int c = wave * 4 + j;                  // chunk 0..15
        gaj[j] = A + (bm + c * 8 + rr) * (long)K + ck;
        lAo[j] = c * 512;
    }
    const u16* gbj[6];                               // B: 24 chunks, 6/wave
    int lBo[6];
#pragma unroll
    for (int j = 0; j < 6; ++j) {
        const int c = wave * 6 + j;                  // chunk 0..23
        const int g = c >> 2;                        // gate
        const int r = (c & 3) * 8 + rr;              // row in gate tile 0..31
        gbj[j] = Wcat + ((long)g * 1024 + bn + r) * (long)K + ck;
        lBo[j] = c * 512;
    }

    auto stage = [&](int t_, int b_) {
        const long kof = (long)t_ * 64;
#pragma unroll
        for (int j = 0; j < 4; ++j)
            GLDS16(gaj[j] + kof, &As[b_ * 8192 + lAo[j]]);
#pragma unroll
        for (int j = 0; j < 6; ++j)
            GLDS16(gbj[j] + kof, &Bs[b_ * 12288 + lBo[j]]);
    };

    const int mh = (wave >> 1) * 64;                 // wave m-half
    const int nb = (wave & 1) * 16;                  // wave n-half
    const int l7 = l15 & 7;
    const int nk = K >> 6;                           // 16

    stage(0, 0);    // 10 loads
    stage(1, 1);    // 10 loads -> 20 in flight

    for (int t = 0; t < nk; ++t) {
        const int cur = t & 1;
        if (t + 1 < nk) asm volatile("s_waitcnt vmcnt(10)" ::: "memory");
        else            asm volatile("s_waitcnt vmcnt(0)"  ::: "memory");
        __builtin_amdgcn_s_barrier();

        const int ab = cur * 8192;     // buffer base (u16), mult of 128 B
        const int bb = cur * 12288;

        // ---- ks = 0: read + MFMA (reads complete before 2nd barrier)
        {
            const int so = (quad ^ l7) * 8;
            bf16x8 af[4];
#pragma unroll
            for (int t4 = 0; t4 < 4; ++t4)
                af[t4] = *(const bf16x8*)&As[ab + (mh + t4 * 16 + l15) * 64 + so];
#pragma unroll
            for (int g = 0; g < 6; ++g) {
                const bf16x8 bfrag =
                    *(const bf16x8*)&Bs[bb + (g * 32 + nb + l15) * 64 + so];
#pragma unroll
                for (int t4 = 0; t4 < 4; ++t4)
                    acc[g][t4] = __builtin_amdgcn_mfma_f32_16x16x32_bf16(
                        af[t4], bfrag, acc[g][t4], 0, 0, 0);
            }
        }
        // ---- ks = 1: reads only, then release the buffer
        bf16x8 af1[4], bf1[6];
        {
            const int so = ((4 + quad) ^ l7) * 8;
#pragma unroll
            for (int t4 = 0; t4 < 4; ++t4)
                af1[t4] = *(const bf16x8*)&As[ab + (mh + t4 * 16 + l15) * 64 + so];
#pragma unroll
            for (int g = 0; g < 6; ++g)
                bf1[g] = *(const bf16x8*)&Bs[bb + (g * 32 + nb + l15) * 64 + so];
        }
        asm volatile("s_waitcnt lgkmcnt(0)" ::: "memory");
        __builtin_amdgcn_s_barrier();
        if (t + 2 < nk) stage(t + 2, cur);

        // ---- ks = 1 MFMAs (cover the just-issued loads)
#pragma unroll
        for (int g = 0; g < 6; ++g)
#pragma unroll
            for (int t4 = 0; t4 < 4; ++t4)
                acc[g][t4] = __builtin_amdgcn_mfma_f32_16x16x32_bf16(
                    af1[t4], bf1[g], acc[g][t4], 0, 0, 0);
    }

    // C/D layout: col = lane&15, row = quad*4 + reg. One n per lane.
    const long n = bn + nb + l15;
    const float bqn = bq_[n], bkn = bk_[n], bvn = bv_[n];
    const float bin = bi_[n], bfn = bf_[n], bon = bo_[n];
#pragma unroll
    for (int t = 0; t < 4; ++t) {
        const long m0 = bm + mh + t * 16 + quad * 4;
#pragma unroll
        for (int r = 0; r < 4; ++r) {
            const float qf = acc[0][t][r] + bqn;
            const float kf = (acc[1][t][r] + bkn) * 0.125f;
            const float vf = acc[2][t][r] + bvn;
            const float fi = acc[3][t][r] + bin;
            const float ff = acc[4][t][r] + bfn;
            const float osig = sigmoidf(acc[5][t][r] + bon);
            const float mx = fmaxf(ff, fi);
            const float fe = __expf(ff - mx);
            const float ct = fe * vf * kf;
            const float h  = osig * (ct * qf) / fmaxf(fabsf(kf * qf), 1.0f);
            ht[(m0 + r) * N + n] = f2bf(h);
        }
    }
}

// LayerNorm over 1024 cols, fp32 in -> bf16 out. One 256-thread block per row.
__global__ __launch_bounds__(256) void ln_in_kernel(
    const float* __restrict__ x, const float* __restrict__ g,
    const float* __restrict__ b, u16* __restrict__ xn)
{
    const long row = blockIdx.x;
    const int  tid = threadIdx.x;
    const float4 v = ((const float4*)(x + row * 1024))[tid];
    float s  = v.x + v.y + v.z + v.w;
    float s2 = v.x * v.x + v.y * v.y + v.z * v.z + v.w * v.w;
#pragma unroll
    for (int off = 32; off > 0; off >>= 1) {
        s  += __shfl_down(s, off);
        s2 += __shfl_down(s2, off);
    }
    __shared__ float red[8];
    const int wave = tid >> 6;
    if ((tid & 63) == 0) { red[wave] = s; red[4 + wave] = s2; }
    __syncthreads();
    if (tid == 0) {
        const float S  = red[0] + red[1] + red[2] + red[3];
        const float S2 = red[4] + red[5] + red[6] + red[7];
        const float mu = S * (1.0f / 1024.0f);
        const float var = S2 * (1.0f / 1024.0f) - mu * mu;
        red[0] = mu; red[1] = rsqrtf(var + 1e-3f);
    }
    __syncthreads();
    const float mu = red[0], rstd = red[1];
    const int c = tid * 4;
    u16x4 o;
    o.x = f2bf((v.x - mu) * rstd * g[c + 0] + b[c + 0]);
    o.y = f2bf((v.y - mu) * rstd * g[c + 1] + b[c + 1]);
    o.z = f2bf((v.z - mu) * rstd * g[c + 2] + b[c + 2]);
    o.w = f2bf((v.w - mu) * rstd * g[c + 3] + b[c + 3]);
    *(u16x4*)(xn + row * 1024 + c) = o;
}

// transpose + f32->bf16: W[K,N] -> Wt[N,K]
__global__ __launch_bounds__(256) void convT_kernel(
    const float* __restrict__ W, u16* __restrict__ Wt, int K, int N)
{
    __shared__ float t[32][33];
    const int tx = threadIdx.x & 31;
    const int ty = threadIdx.x >> 5;
    const long bn = (long)blockIdx.x * 32;
    const long bk = (long)blockIdx.y * 32;
#pragma unroll
    for (int j = 0; j < 4; ++j)
        t[ty + j * 8][tx] = W[(bk + ty + j * 8) * N + bn + tx];
    __syncthreads();
#pragma unroll
    for (int j = 0; j < 4; ++j)
        Wt[(bn + ty + j * 8) * K + bk + tx] = f2bf(t[tx][ty + j * 8]);
}

// LN2 over ht rows + sigmoid(xadj) product. y may alias ht (same-thread r/w).
__global__ __launch_bounds__(256) void ln2_kernel(
    const u16* __restrict__ ht, const u16* __restrict__ xadj,
    const float* __restrict__ g2, const float* __restrict__ b2,
    u16* __restrict__ y)
{
    const long base = (long)blockIdx.x * 1024;
    const int  tid = threadIdx.x;
    const int  c = tid * 4;
    const u16x4 hv = *(const u16x4*)&ht[base + c];
    const u16x4 xv = *(const u16x4*)&xadj[base + c];

    float h[4];
    float s = 0.0f, s2 = 0.0f;
#pragma unroll
    for (int j = 0; j < 4; ++j) {
        h[j] = bf2f(hv[j]);
        s += h[j]; s2 += h[j] * h[j];
    }
#pragma unroll
    for (int off = 32; off > 0; off >>= 1) {
        s  += __shfl_down(s, off);
        s2 += __shfl_down(s2, off);
    }
    __shared__ float red[8];
    const int wave = tid >> 6;
    if ((tid & 63) == 0) { red[wave] = s; red[4 + wave] = s2; }
    __syncthreads();
    if (tid == 0) {
        const float S  = red[0] + red[1] + red[2] + red[3];
        const float S2 = red[4] + red[5] + red[6] + red[7];
        const float mu = S * (1.0f / 1024.0f);
        const float var = S2 * (1.0f / 1024.0f) - mu * mu;
        red[0] = mu; red[1] = rsqrtf(var + 1e-3f);
    }
    __syncthreads();
    const float mu = red[0], rstd = red[1];
    u16x4 o;
#pragma unroll
    for (int j = 0; j < 4; ++j)
        o[j] = f2bf(((h[j] - mu) * rstd * g2[c + j] + b2[c + j]) * sigmoidf(bf2f(xv[j])));
    *(u16x4*)&y[base + c] = o;
}

extern "C" void kernel_launch(void* const* d_in, const int* in_sizes, int n_in,
                              void* d_out, int out_size, void* d_ws, size_t ws_size,
                              hipStream_t stream)
{
    const float* x    = (const float*)d_in[0];
    const float* g1   = (const float*)d_in[1];
    const float* b1   = (const float*)d_in[2];
    const float* Wup  = (const float*)d_in[3];
    const float* bup  = (const float*)d_in[4];
    const float* Wadj = (const float*)d_in[5];
    const float* badj = (const float*)d_in[6];
    const float* Wq = (const float*)d_in[7];   const float* bq = (const float*)d_in[8];
    const float* Wk = (const float*)d_in[9];   const float* bk = (const float*)d_in[10];
    const float* Wv = (const float*)d_in[11];  const float* bv = (const float*)d_in[12];
    const float* Wi = (const float*)d_in[13];  const float* bi = (const float*)d_in[14];
    const float* Wf = (const float*)d_in[15];  const float* bf = (const float*)d_in[16];
    const float* Wo = (const float*)d_in[17];  const float* bo = (const float*)d_in[18];
    const float* g2 = (const float*)d_in[19];  const float* b2 = (const float*)d_in[20];
    const float* Wdn = (const float*)d_in[21]; const float* bdn = (const float*)d_in[22];

    const int M = 8 * 2048;     // 16384 tokens
    const int D = 1024, P = 2048, H = 1024;

    char* ws = (char*)d_ws;
    const size_t MB = 1024 * 1024;
    u16* xn    = (u16*)(ws + 0);
    u16* xup   = (u16*)(ws + 32 * MB);
    u16* xadj  = (u16*)(ws + 96 * MB);
    u16* htb   = (u16*)(ws + 0);          // reuse xn (dead after up-GEMM)
    u16* yb    = (u16*)(ws + 0);          // alias ht (same-thread read-then-write)
    u16* WupT  = (u16*)(ws + 128 * MB);   // [2048,1024] 4MB
    u16* WadjT = (u16*)(ws + 132 * MB);   // [1024,2048] 4MB
    u16* Wcat  = (u16*)(ws + 136 * MB);   // [6*1024,1024] 12MB, order q,k,v,i,f,o
    u16* WdnT  = (u16*)(ws + 148 * MB);   // [1024,1024] 2MB -> ends at 150 MiB

    // 1) LN1
    ln_in_kernel<<<M, 256, 0, stream>>>(x, g1, b1, xn);

    // 2) weight transpose+convert (gates go into concatenated Wcat)
    convT_kernel<<<dim3(P / 32, D / 32), 256, 0, stream>>>(Wup,  WupT,  D, P);
    convT_kernel<<<dim3(H / 32, P / 32), 256, 0, stream>>>(Wadj, WadjT, P, H);
    convT_kernel<<<dim3(H / 32, H / 32), 256, 0, stream>>>(Wq, Wcat + 0 * H * H, H, H);
    convT_kernel<<<dim3(H / 32, H / 32), 256, 0, stream>>>(Wk, Wcat + 1 * H * H, H, H);
    convT_kernel<<<dim3(H / 32, H / 32), 256, 0, stream>>>(Wv, Wcat + 2 * H * H, H, H);
    convT_kernel<<<dim3(H / 32, H / 32), 256, 0, stream>>>(Wi, Wcat + 3 * H * H, H, H);
    convT_kernel<<<dim3(H / 32, H / 32), 256, 0, stream>>>(Wf, Wcat + 4 * H * H, H, H);
    convT_kernel<<<dim3(H / 32, H / 32), 256, 0, stream>>>(Wo, Wcat + 5 * H * H, H, H);
    convT_kernel<<<dim3(D / 32, H / 32), 256, 0, stream>>>(Wdn, WdnT, H, D);

    // 3) up- and adj-GEMMs
    gemm_bt<0><<<dim3(P / BN, M / BM), 256, 0, stream>>>(xn,  WupT,  bup,  nullptr, xup,  M, P, D, 1.0f);
    gemm_bt<0><<<dim3(H / BN, M / BM), 256, 0, stream>>>(xup, WadjT, badj, nullptr, xadj, M, H, P, 1.0f);

    // 4) fused six-gate GEMM + gate math -> ht (128M x 32N x 6g, BK=64)
    gemm_gates<<<dim3(H / 32, M / 128), 256, 0, stream>>>(
        xadj, Wcat, bq, bk, bv, bi, bf, bo, htb, M, H, H);

    // 5) LN2 + sigmoid(xadj) -> y
    ln2_kernel<<<M, 256, 0, stream>>>(htb, xadj, g2, b2, yb);

    // 6) down-proj + bias + residual, fp32 out
    gemm_bt<1><<<dim3(D / BN, M / BM), 256, 0, stream>>>(yb, WdnT, bdn, x, (float*)d_out, M, D, H, 1.0f);
}

// Round 3
// 569.078 us; speedup vs baseline: 1.4377x; 1.1640x over previous
//
#include <hip/hip_runtime.h>

// mLSTM block, bf16-MFMA, R7: algebraic fold of up+adj projections.
// There is no nonlinearity between W_up and W_adj, so
//   x_adj = x_norm @ (W_up @ W_adj) + (b_up @ W_adj + b_adj)
// One [M,1024]@[1024,1024] GEMM (34.4 GFLOP) replaces two token-GEMMs
// (137.4 GFLOP) and kills the 128 MB xup round-trip. W_combT = WadjT @ Wup
// is a tiny 64-block GEMM; b_comb is a 1024-row dot-reduce.
// Both GEMM kernels keep the R6 2-deep counted-vmcnt pipeline (never drain
// vmcnt in the main loop).
// Tokens M = 16384, D = 1024, P = 2048, H = 1024.
//
// LDS swizzle (gemm_bt, rows = 64 B = 4 chunks of 16 B): chunk c of row r
// stored at slot c ^ ((r>>1)&3), via swizzled SOURCE address
// (global_load_lds forces dest = base + lane*16). Readers use
// quad ^ ((l15>>1)&3). Measured 0 conflicts.
//
// gemm_gates swizzle (rows = 128 B = 8 chunks of 16 B): slot = c ^ (r&7);
// staging lane covers row lane>>3, slot lane&7, source chunk
// (lane&7)^(lane>>3). Readers use (ks*4+quad)^(l15&7). Measured 0 conflicts.
//
// Workspace (MiB offsets), total 150 MiB:
//   [0,32)    xn -> ht (xn dead after xadj-GEMM) -> y (same-thread r/w alias)
//   [32,34)   WcombT [1024,1024]   (freed xup region)
//   [36,36+4K) b_comb (f32[1024])
//   [96,128)  xadj
//   [128,132) Wup_bf [1024,2048] (row-major, no transpose)
//   [132,136) WadjT  [1024,2048]
//   [136,148) Wcat   [6*1024,1024] (order q,k,v,i,f,o)
//   [148,150) WdnT   [1024,1024]

typedef unsigned short u16;
typedef __attribute__((ext_vector_type(4))) unsigned short u16x4;
typedef __attribute__((ext_vector_type(8))) unsigned short u16x8;
typedef __attribute__((ext_vector_type(8))) __bf16 bf16x8;
typedef __attribute__((ext_vector_type(4))) float f32x4;

__device__ __forceinline__ float bf2f(u16 u) {
    union { unsigned int i; float f; } c; c.i = ((unsigned int)u) << 16; return c.f;
}
__device__ __forceinline__ u16 f2bf(float f) {
    union { float f; unsigned int i; } c; c.f = f;
    unsigned int lsb = (c.i >> 16) & 1u;
    c.i += 0x7fffu + lsb;                 // round-to-nearest-even
    return (u16)(c.i >> 16);
}
__device__ __forceinline__ float sigmoidf(float z) {
    return 1.0f / (1.0f + __expf(-z));
}

// async global->LDS, 16B per lane; LDS dest = wave-uniform base + lane*16
#define GLDS16(gp, lp)                                                        \
    __builtin_amdgcn_global_load_lds(                                         \
        (__attribute__((address_space(1))) void*)(void*)(gp),                 \
        (__attribute__((address_space(3))) void*)(lp), 16, 0, 0)

#define BM 128
#define BN 128
#define BK 32

// C[M,N] = A[M,K] @ B[K,N] with Bt = B^T stored [N,K], all bf16, fp32 acc.
// MODE 0: out bf16 = (acc + bias[n]) * scale
// MODE 1: out f32  = (acc + bias[n]) * scale + resid[m*N+n]
// MODE 2: out bf16 = acc * scale              (no bias; bias may be nullptr)
template <int MODE>
__global__ __launch_bounds__(256) void gemm_bt(
    const u16* __restrict__ A, const u16* __restrict__ Bt,
    const float* __restrict__ bias, const float* __restrict__ resid,
    void* __restrict__ out, int M, int N, int K, float scale)
{
    __shared__ __align__(16) u16 As[2 * BM * BK];   // 2 x 8 KB
    __shared__ __align__(16) u16 Bs[2 * BN * BK];   // 2 x 8 KB

    const int tid  = threadIdx.x;
    const int lane = tid & 63;
    const int wave = tid >> 6;
    const int l15  = lane & 15;
    const int quad = lane >> 4;

    const long bm = (long)blockIdx.y * BM;
    const long bn = (long)blockIdx.x * BN;
    const int  wm = (wave >> 1) * 64;   // wave's 64x64 quadrant
    const int  wn = (wave & 1) * 64;

    f32x4 acc[4][4] = {};

    // staging: thread tid covers row tid>>2; SOURCE chunk is swizzled so the
    // identity LDS placement (lane*16) realizes the XOR-swizzled layout.
    const int  r0 = tid >> 2;
    const int  ck = (((tid & 3) ^ ((tid >> 3) & 3)) * 8);
    const u16* ga0 = A  + (bm + r0) * (long)K + ck;
    const u16* gb0 = Bt + (bn + r0) * (long)K + ck;
    const int  ldst = wave * 512;        // wave's dest inside a buffer (u16)

    auto stage = [&](int t_, int b_) {
        const long kof = (long)t_ * BK;
        u16* dA = &As[b_ * (BM * BK) + ldst];
        u16* dB = &Bs[b_ * (BN * BK) + ldst];
        GLDS16(ga0 + kof, dA);
        GLDS16(ga0 + kof + 64 * (long)K, dA + 2048);
        GLDS16(gb0 + kof, dB);
        GLDS16(gb0 + kof + 64 * (long)K, dB + 2048);
    };

    const int q8s = (quad ^ ((l15 >> 1) & 3)) * 8;   // swizzled chunk offset
    const int nk  = K / BK;

    stage(0, 0);    // 4 loads
    stage(1, 1);    // 4 loads -> 8 in flight

    for (int t = 0; t < nk; ++t) {
        const int cur = t & 1;
        if (t + 1 < nk) asm volatile("s_waitcnt vmcnt(4)" ::: "memory");
        else            asm volatile("s_waitcnt vmcnt(0)" ::: "memory");
        __builtin_amdgcn_s_barrier();

        bf16x8 af[4], bfr[4];
#pragma unroll
        for (int t4 = 0; t4 < 4; ++t4) {
            af[t4]  = *(const bf16x8*)&As[cur * (BM * BK) + (wm + t4 * 16 + l15) * BK + q8s];
            bfr[t4] = *(const bf16x8*)&Bs[cur * (BN * BK) + (wn + t4 * 16 + l15) * BK + q8s];
        }
        asm volatile("s_waitcnt lgkmcnt(0)" ::: "memory");
        __builtin_amdgcn_s_barrier();
        if (t + 2 < nk) stage(t + 2, cur);

#pragma unroll
        for (int mt = 0; mt < 4; ++mt)
#pragma unroll
            for (int nt = 0; nt < 4; ++nt)
                acc[mt][nt] = __builtin_amdgcn_mfma_f32_16x16x32_bf16(
                    af[mt], bfr[nt], acc[mt][nt], 0, 0, 0);
    }

    // C/D layout: col = lane&15, row = quad*4 + reg
#pragma unroll
    for (int nt = 0; nt < 4; ++nt) {
        const long n  = bn + wn + nt * 16 + l15;
        const float bv = (MODE == 2) ? 0.0f : bias[n];
#pragma unroll
        for (int mt = 0; mt < 4; ++mt) {
            const long m0 = bm + wm + mt * 16 + quad * 4;
#pragma unroll
            for (int r = 0; r < 4; ++r) {
                const long idx = (m0 + r) * N + n;
                const float val = (acc[mt][nt][r] + bv) * scale;
                if (MODE == 1) ((float*)out)[idx] = val + resid[idx];
                else           ((u16*)out)[idx] = f2bf(val);
            }
        }
    }
}

// Fused 6-way gate GEMM + mLSTM gate math.
// A = xadj [M,K], Wcat = 6 gate weights transposed, [6*1024, K] (order
// q,k,v,i,f,o). Block = 128(M) x 32(N) of ALL six projections, BK=64,
// 256 threads / 4 waves. Wave w owns m-half (w>>1)*64 and n-half (w&1)*16:
// per BK-step 8 A-frag reads + 12 B-frag reads feed 48 MFMAs. f32 accs,
// gate math in-register, writes ht bf16 [M,1024]. 2-deep pipelined.
__global__ __launch_bounds__(256) void gemm_gates(
    const u16* __restrict__ A, const u16* __restrict__ Wcat,
    const float* __restrict__ bq_, const float* __restrict__ bk_,
    const float* __restrict__ bv_, const float* __restrict__ bi_,
    const float* __restrict__ bf_, const float* __restrict__ bo_,
    u16* __restrict__ ht, int M, int N, int K)
{
    __shared__ __align__(16) u16 As[2 * 128 * 64];       // 2 x 16 KB
    __shared__ __align__(16) u16 Bs[2 * 6 * 32 * 64];    // 2 x 24 KB

    const int tid  = threadIdx.x;
    const int lane = tid & 63;
    const int wave = tid >> 6;          // 0..3
    const int l15  = lane & 15;
    const int quad = lane >> 4;

    const long bm = (long)blockIdx.y * 128;
    const long bn = (long)blockIdx.x * 32;

    f32x4 acc[6][4] = {};

    // ---- staging: 1 KB wave-chunks of 8 rows (rows are 128 B = 64 u16).
    // lane covers row lane>>3 of the chunk, slot lane&7; source chunk is
    // (lane&7)^(lane>>3) so identity LDS placement realizes slot = c^(r&7).
    const int  rr = lane >> 3;                       // row within 8-row group
    const int  ck = (((lane & 7) ^ rr) * 8);         // swizzled source (u16)

    const u16* gaj[4];                               // A: 16 chunks, 4/wave
    int lAo[4];
#pragma unroll
    for (int j = 0; j < 4; ++j) {
        const int c = wave * 4 + j;                  // chunk 0..15
        gaj[j] = A + (bm + c * 8 + rr) * (long)K + ck;
        lAo[j] = c * 512;
    }
    const u16* gbj[6];                               // B: 24 chunks, 6/wave
    int lBo[6];
#pragma unroll
    for (int j = 0; j < 6; ++j) {
        const int c = wave * 6 + j;                  // chunk 0..23
        const int g = c >> 2;                        // gate
        const int r = (c & 3) * 8 + rr;              // row in gate tile 0..31
        gbj[j] = Wcat + ((long)g * 1024 + bn + r) * (long)K + ck;
        lBo[j] = c * 512;
    }

    auto stage = [&](int t_, int b_) {
        const long kof = (long)t_ * 64;
#pragma unroll
        for (int j = 0; j < 4; ++j)
            GLDS16(gaj[j] + kof, &As[b_ * 8192 + lAo[j]]);
#pragma unroll
        for (int j = 0; j < 6; ++j)
            GLDS16(gbj[j] + kof, &Bs[b_ * 12288 + lBo[j]]);
    };

    const int mh = (wave >> 1) * 64;                 // wave m-half
    const int nb = (wave & 1) * 16;                  // wave n-half
    const int l7 = l15 & 7;
    const int nk = K >> 6;                           // 16

    stage(0, 0);    // 10 loads
    stage(1, 1);    // 10 loads -> 20 in flight

    for (int t = 0; t < nk; ++t) {
        const int cur = t & 1;
        if (t + 1 < nk) asm volatile("s_waitcnt vmcnt(10)" ::: "memory");
        else            asm volatile("s_waitcnt vmcnt(0)"  ::: "memory");
        __builtin_amdgcn_s_barrier();

        const int ab = cur * 8192;     // buffer base (u16), mult of 128 B
        const int bb = cur * 12288;

        // ---- ks = 0: read + MFMA (reads complete before 2nd barrier)
        {
            const int so = (quad ^ l7) * 8;
            bf16x8 af[4];
#pragma unroll
            for (int t4 = 0; t4 < 4; ++t4)
                af[t4] = *(const bf16x8*)&As[ab + (mh + t4 * 16 + l15) * 64 + so];
#pragma unroll
            for (int g = 0; g < 6; ++g) {
                const bf16x8 bfrag =
                    *(const bf16x8*)&Bs[bb + (g * 32 + nb + l15) * 64 + so];
#pragma unroll
                for (int t4 = 0; t4 < 4; ++t4)
                    acc[g][t4] = __builtin_amdgcn_mfma_f32_16x16x32_bf16(
                        af[t4], bfrag, acc[g][t4], 0, 0, 0);
            }
        }
        // ---- ks = 1: reads only, then release the buffer
        bf16x8 af1[4], bf1[6];
        {
            const int so = ((4 + quad) ^ l7) * 8;
#pragma unroll
            for (int t4 = 0; t4 < 4; ++t4)
                af1[t4] = *(const bf16x8*)&As[ab + (mh + t4 * 16 + l15) * 64 + so];
#pragma unroll
            for (int g = 0; g < 6; ++g)
                bf1[g] = *(const bf16x8*)&Bs[bb + (g * 32 + nb + l15) * 64 + so];
        }
        asm volatile("s_waitcnt lgkmcnt(0)" ::: "memory");
        __builtin_amdgcn_s_barrier();
        if (t + 2 < nk) stage(t + 2, cur);

        // ---- ks = 1 MFMAs (cover the just-issued loads)
#pragma unroll
        for (int g = 0; g < 6; ++g)
#pragma unroll
            for (int t4 = 0; t4 < 4; ++t4)
                acc[g][t4] = __builtin_amdgcn_mfma_f32_16x16x32_bf16(
                    af1[t4], bf1[g], acc[g][t4], 0, 0, 0);
    }

    // C/D layout: col = lane&15, row = quad*4 + reg. One n per lane.
    const long n = bn + nb + l15;
    const float bqn = bq_[n], bkn = bk_[n], bvn = bv_[n];
    const float bin = bi_[n], bfn = bf_[n], bon = bo_[n];
#pragma unroll
    for (int t = 0; t < 4; ++t) {
        const long m0 = bm + mh + t * 16 + quad * 4;
#pragma unroll
        for (int r = 0; r < 4; ++r) {
            const float qf = acc[0][t][r] + bqn;
            const float kf = (acc[1][t][r] + bkn) * 0.125f;
            const float vf = acc[2][t][r] + bvn;
            const float fi = acc[3][t][r] + bin;
            const float ff = acc[4][t][r] + bfn;
            const float osig = sigmoidf(acc[5][t][r] + bon);
            const float mx = fmaxf(ff, fi);
            const float fe = __expf(ff - mx);
            const float ct = fe * vf * kf;
            const float h  = osig * (ct * qf) / fmaxf(fabsf(kf * qf), 1.0f);
            ht[(m0 + r) * N + n] = f2bf(h);
        }
    }
}

// LayerNorm over 1024 cols, fp32 in -> bf16 out. One 256-thread block per row.
__global__ __launch_bounds__(256) void ln_in_kernel(
    const float* __restrict__ x, const float* __restrict__ g,
    const float* __restrict__ b, u16* __restrict__ xn)
{
    const long row = blockIdx.x;
    const int  tid = threadIdx.x;
    const float4 v = ((const float4*)(x + row * 1024))[tid];
    float s  = v.x + v.y + v.z + v.w;
    float s2 = v.x * v.x + v.y * v.y + v.z * v.z + v.w * v.w;
#pragma unroll
    for (int off = 32; off > 0; off >>= 1) {
        s  += __shfl_down(s, off);
        s2 += __shfl_down(s2, off);
    }
    __shared__ float red[8];
    const int wave = tid >> 6;
    if ((tid & 63) == 0) { red[wave] = s; red[4 + wave] = s2; }
    __syncthreads();
    if (tid == 0) {
        const float S  = red[0] + red[1] + red[2] + red[3];
        const float S2 = red[4] + red[5] + red[6] + red[7];
        const float mu = S * (1.0f / 1024.0f);
        const float var = S2 * (1.0f / 1024.0f) - mu * mu;
        red[0] = mu; red[1] = rsqrtf(var + 1e-3f);
    }
    __syncthreads();
    const float mu = red[0], rstd = red[1];
    const int c = tid * 4;
    u16x4 o;
    o.x = f2bf((v.x - mu) * rstd * g[c + 0] + b[c + 0]);
    o.y = f2bf((v.y - mu) * rstd * g[c + 1] + b[c + 1]);
    o.z = f2bf((v.z - mu) * rstd * g[c + 2] + b[c + 2]);
    o.w = f2bf((v.w - mu) * rstd * g[c + 3] + b[c + 3]);
    *(u16x4*)(xn + row * 1024 + c) = o;
}

// transpose + f32->bf16: W[K,N] -> Wt[N,K]
__global__ __launch_bounds__(256) void convT_kernel(
    const float* __restrict__ W, u16* __restrict__ Wt, int K, int N)
{
    __shared__ float t[32][33];
    const int tx = threadIdx.x & 31;
    const int ty = threadIdx.x >> 5;
    const long bn = (long)blockIdx.x * 32;
    const long bk = (long)blockIdx.y * 32;
#pragma unroll
    for (int j = 0; j < 4; ++j)
        t[ty + j * 8][tx] = W[(bk + ty + j * 8) * N + bn + tx];
    __syncthreads();
#pragma unroll
    for (int j = 0; j < 4; ++j)
        Wt[(bn + ty + j * 8) * K + bk + tx] = f2bf(t[tx][ty + j * 8]);
}

// plain f32 -> bf16 convert (no transpose), 4 elems/thread
__global__ __launch_bounds__(256) void convB_kernel(
    const float* __restrict__ W, u16* __restrict__ Wb)
{
    const long i = ((long)blockIdx.x * 256 + threadIdx.x) * 4;
    const float4 v = *(const float4*)(W + i);
    u16x4 o;
    o.x = f2bf(v.x); o.y = f2bf(v.y); o.z = f2bf(v.z); o.w = f2bf(v.w);
    *(u16x4*)(Wb + i) = o;
}

// b_comb[h] = dot(WadjT[h,:], b_up) + b_adj[h].  One block per h.
__global__ __launch_bounds__(256) void bcomb_kernel(
    const u16* __restrict__ WadjT, const float* __restrict__ bup,
    const float* __restrict__ badj, float* __restrict__ bcomb)
{
    const long h = blockIdx.x;
    const int  tid = threadIdx.x;
    const int  p = tid * 8;
    const u16x8 w = *(const u16x8*)&WadjT[h * 2048 + p];
    float s = 0.0f;
#pragma unroll
    for (int j = 0; j < 8; ++j) s += bf2f(w[j]) * bup[p + j];
#pragma unroll
    for (int off = 32; off > 0; off >>= 1) s += __shfl_down(s, off);
    __shared__ float red[4];
    const int wave = tid >> 6;
    if ((tid & 63) == 0) red[wave] = s;
    __syncthreads();
    if (tid == 0)
        bcomb[h] = red[0] + red[1] + red[2] + red[3] + badj[h];
}

// LN2 over ht rows + sigmoid(xadj) product. y may alias ht (same-thread r/w).
__global__ __launch_bounds__(256) void ln2_kernel(
    const u16* __restrict__ ht, const u16* __restrict__ xadj,
    const float* __restrict__ g2, const float* __restrict__ b2,
    u16* __restrict__ y)
{
    const long base = (long)blockIdx.x * 1024;
    const int  tid = threadIdx.x;
    const int  c = tid * 4;
    const u16x4 hv = *(const u16x4*)&ht[base + c];
    const u16x4 xv = *(const u16x4*)&xadj[base + c];

    float h[4];
    float s = 0.0f, s2 = 0.0f;
#pragma unroll
    for (int j = 0; j < 4; ++j) {
        h[j] = bf2f(hv[j]);
        s += h[j]; s2 += h[j] * h[j];
    }
#pragma unroll
    for (int off = 32; off > 0; off >>= 1) {
        s  += __shfl_down(s, off);
        s2 += __shfl_down(s2, off);
    }
    __shared__ float red[8];
    const int wave = tid >> 6;
    if ((tid & 63) == 0) { red[wave] = s; red[4 + wave] = s2; }
    __syncthreads();
    if (tid == 0) {
        const float S  = red[0] + red[1] + red[2] + red[3];
        const float S2 = red[4] + red[5] + red[6] + red[7];
        const float mu = S * (1.0f / 1024.0f);
        const float var = S2 * (1.0f / 1024.0f) - mu * mu;
        red[0] = mu; red[1] = rsqrtf(var + 1e-3f);
    }
    __syncthreads();
    const float mu = red[0], rstd = red[1];
    u16x4 o;
#pragma unroll
    for (int j = 0; j < 4; ++j)
        o[j] = f2bf(((h[j] - mu) * rstd * g2[c + j] + b2[c + j]) * sigmoidf(bf2f(xv[j])));
    *(u16x4*)&y[base + c] = o;
}

extern "C" void kernel_launch(void* const* d_in, const int* in_sizes, int n_in,
                              void* d_out, int out_size, void* d_ws, size_t ws_size,
                              hipStream_t stream)
{
    const float* x    = (const float*)d_in[0];
    const float* g1   = (const float*)d_in[1];
    const float* b1   = (const float*)d_in[2];
    const float* Wup  = (const float*)d_in[3];
    const float* bup  = (const float*)d_in[4];
    const float* Wadj = (const float*)d_in[5];
    const float* badj = (const float*)d_in[6];
    const float* Wq = (const float*)d_in[7];   const float* bq = (const float*)d_in[8];
    const float* Wk = (const float*)d_in[9];   const float* bk = (const float*)d_in[10];
    const float* Wv = (const float*)d_in[11];  const float* bv = (const float*)d_in[12];
    const float* Wi = (const float*)d_in[13];  const float* bi = (const float*)d_in[14];
    const float* Wf = (const float*)d_in[15];  const float* bf = (const float*)d_in[16];
    const float* Wo = (const float*)d_in[17];  const float* bo = (const float*)d_in[18];
    const float* g2 = (const float*)d_in[19];  const float* b2 = (const float*)d_in[20];
    const float* Wdn = (const float*)d_in[21]; const float* bdn = (const float*)d_in[22];

    const int M = 8 * 2048;     // 16384 tokens
    const int D = 1024, P = 2048, H = 1024;

    char* ws = (char*)d_ws;
    const size_t MB = 1024 * 1024;
    u16* xn     = (u16*)(ws + 0);
    u16* htb    = (u16*)(ws + 0);          // reuse xn (dead after xadj-GEMM)
    u16* yb     = (u16*)(ws + 0);          // alias ht (same-thread read-then-write)
    u16* WcombT = (u16*)(ws + 32 * MB);    // [1024,1024] 2MB (freed xup region)
    float* bcomb = (float*)(ws + 36 * MB); // f32[1024]
    u16* xadj   = (u16*)(ws + 96 * MB);
    u16* Wup_bf = (u16*)(ws + 128 * MB);   // [1024,2048] row-major 4MB
    u16* WadjT  = (u16*)(ws + 132 * MB);   // [1024,2048] 4MB
    u16* Wcat   = (u16*)(ws + 136 * MB);   // [6*1024,1024] 12MB, order q,k,v,i,f,o
    u16* WdnT   = (u16*)(ws + 148 * MB);   // [1024,1024] 2MB -> ends at 150 MiB

    // 1) LN1
    ln_in_kernel<<<M, 256, 0, stream>>>(x, g1, b1, xn);

    // 2) weight prep
    convB_kernel<<<(D * P) / (256 * 4), 256, 0, stream>>>(Wup, Wup_bf);
    convT_kernel<<<dim3(H / 32, P / 32), 256, 0, stream>>>(Wadj, WadjT, P, H);
    convT_kernel<<<dim3(H / 32, H / 32), 256, 0, stream>>>(Wq, Wcat + 0 * H * H, H, H);
    convT_kernel<<<dim3(H / 32, H / 32), 256, 0, stream>>>(Wk, Wcat + 1 * H * H, H, H);
    convT_kernel<<<dim3(H / 32, H / 32), 256, 0, stream>>>(Wv, Wcat + 2 * H * H, H, H);
    convT_kernel<<<dim3(H / 32, H / 32), 256, 0, stream>>>(Wi, Wcat + 3 * H * H, H, H);
    convT_kernel<<<dim3(H / 32, H / 32), 256, 0, stream>>>(Wf, Wcat + 4 * H * H, H, H);
    convT_kernel<<<dim3(H / 32, H / 32), 256, 0, stream>>>(Wo, Wcat + 5 * H * H, H, H);
    convT_kernel<<<dim3(D / 32, H / 32), 256, 0, stream>>>(Wdn, WdnT, H, D);
    bcomb_kernel<<<H, 256, 0, stream>>>(WadjT, bup, badj, bcomb);

    // 3) W_combT = WadjT @ Wup_bf  ([H,P] @ [P,D] -> [H,D], i.e. (Wup@Wadj)^T)
    gemm_bt<2><<<dim3(D / BN, H / BM), 256, 0, stream>>>(
        WadjT, Wup_bf, nullptr, nullptr, WcombT, H, D, P, 1.0f);

    // 4) xadj = xn @ W_comb + b_comb   (folded up+adj projection)
    gemm_bt<0><<<dim3(H / BN, M / BM), 256, 0, stream>>>(
        xn, WcombT, bcomb, nullptr, xadj, M, H, D, 1.0f);

    // 5) fused six-gate GEMM + gate math -> ht (128M x 32N x 6g, BK=64)
    gemm_gates<<<dim3(H / 32, M / 128), 256, 0, stream>>>(
        xadj, Wcat, bq, bk, bv, bi, bf, bo, htb, M, H, H);

    // 6) LN2 + sigmoid(xadj) -> y
    ln2_kernel<<<M, 256, 0, stream>>>(htb, xadj, g2, b2, yb);

    // 7) down-proj + bias + residual, fp32 out
    gemm_bt<1><<<dim3(D / BN, M / BM), 256, 0, stream>>>(yb, WdnT, bdn, x, (float*)d_out, M, D, H, 1.0f);
}